// Round 4
// baseline (8304.691 us; speedup 1.0000x reference)
//
#include <hip/hip_runtime.h>
#include <hip/hip_fp16.h>

#define B_ 64
#define T_ 512
#define I_ 128
#define H_ 512

typedef _Float16 half2v __attribute__((ext_vector_type(2)));

__device__ __forceinline__ float dot2(unsigned a, unsigned b, float c) {
    return __builtin_amdgcn_fdot2(__builtin_bit_cast(half2v, a),
                                  __builtin_bit_cast(half2v, b), c, false);
}

__device__ __forceinline__ unsigned short f32_to_f16b(float f) {
    _Float16 h = (_Float16)f;
    return __builtin_bit_cast(unsigned short, h);
}

// ---------------------------------------------------------------------------
// Kernel 1: W_hid fp32 [H,H] -> packed f16 pairs, laid out for `recurrent`:
// uint4 element index = (((hh*8 + w)*4 + h_i)*8 + g)*64 + l
//   h = hh*256 + 64*h_i + l ;  pair kp = 32*w + 4*g + m (m = dword in uint4)
// Thread (w,l) of block-half hh loads wv[h_i][g] = Wz4[...*64 + l]: coalesced.
// Also zeroes the 128 sync flags (d_ws is re-poisoned before every launch).
// ---------------------------------------------------------------------------
__global__ void wconv(const float* __restrict__ Whid,
                      unsigned* __restrict__ Wz,
                      unsigned* __restrict__ flags) {
    int p = blockIdx.x * 256 + threadIdx.x;   // dword index, 0..131071
    int m   = p & 3;
    int l   = (p >> 2) & 63;
    int g   = (p >> 8) & 7;
    int h_i = (p >> 11) & 3;
    int w   = (p >> 13) & 7;
    int hh  = p >> 16;
    int h  = hh * 256 + 64 * h_i + l;
    int kp = 32 * w + 4 * g + m;
    float w0 = Whid[h * H_ + 2 * kp];
    float w1 = Whid[h * H_ + 2 * kp + 1];
    half2v hw = { (_Float16)w0, (_Float16)w1 };
    Wz[p] = __builtin_bit_cast(unsigned, hw);
    if (p < 128) flags[p] = 0;
}

// ---------------------------------------------------------------------------
// Kernel 2: v_in[b,t,h] = x[b,t,:] @ W_in[h,:] + b_in[h]  (unchanged)
// ---------------------------------------------------------------------------
__global__ __launch_bounds__(256) void vin_gemm(const float* __restrict__ x,
                                                const float* __restrict__ Win,
                                                const float* __restrict__ bin,
                                                float* __restrict__ vin) {
    __shared__ float xs[64][129];
    __shared__ float wsh[64][129];
    const int tid = threadIdx.x;
    const int m0 = blockIdx.x * 64;
    const int n0 = blockIdx.y * 64;

    #pragma unroll
    for (int r = 0; r < 8; ++r) {
        int gi = r * 256 + tid;
        int row = gi >> 5;
        int c4 = (gi & 31) * 4;
        float4 v = ((const float4*)(x + (size_t)(m0 + row) * I_))[gi & 31];
        xs[row][c4] = v.x; xs[row][c4 + 1] = v.y;
        xs[row][c4 + 2] = v.z; xs[row][c4 + 3] = v.w;
        float4 w = ((const float4*)(Win + (size_t)(n0 + row) * I_))[gi & 31];
        wsh[row][c4] = w.x; wsh[row][c4 + 1] = w.y;
        wsh[row][c4 + 2] = w.z; wsh[row][c4 + 3] = w.w;
    }
    __syncthreads();

    const int ty = tid >> 4, tx = tid & 15;
    float acc[4][4] = {};
    #pragma unroll 4
    for (int k = 0; k < 128; ++k) {
        float a[4], bb[4];
        #pragma unroll
        for (int i = 0; i < 4; ++i) a[i] = xs[ty * 4 + i][k];
        #pragma unroll
        for (int j = 0; j < 4; ++j) bb[j] = wsh[tx * 4 + j][k];
        #pragma unroll
        for (int i = 0; i < 4; ++i)
            #pragma unroll
            for (int j = 0; j < 4; ++j)
                acc[i][j] = fmaf(a[i], bb[j], acc[i][j]);
    }

    float4 bv = ((const float4*)(bin + n0))[tx];
    #pragma unroll
    for (int i = 0; i < 4; ++i) {
        int m = m0 + ty * 4 + i;
        float4 o;
        o.x = acc[i][0] + bv.x; o.y = acc[i][1] + bv.y;
        o.z = acc[i][2] + bv.z; o.w = acc[i][3] + bv.w;
        ((float4*)(vin + (size_t)m * H_ + n0))[tx] = o;
    }
}

// ---------------------------------------------------------------------------
// Kernel 3: recurrence, 2 CUs per batch (h-split), k-split by wave.
// Block j: b = j&63, hh = j>>6 -> h in [256*hh, 256*hh+256).
// Thread (w = t>>6, l = t&63): 4 h {l, l+64, l+128, l+192} x k-slice [64w,64w+64).
// W: 32 uint4 in VGPRs. fr: f16 pairs in LDS (8 broadcast b128/thread/step).
// Partial dots reduced via pbuf[8][256]. fr halves exchanged cross-block via
// agent-scope atomics; per-wave release counter (4 increments/step) avoids
// any circular wait: producers never wait on consumers before signaling.
// ---------------------------------------------------------------------------
__global__ __launch_bounds__(512, 2)
__attribute__((amdgpu_waves_per_eu(2, 2)))
void recurrent(
        const uint4* __restrict__ Wz4,
        const float* __restrict__ vin,
        const float* __restrict__ init_state,
        const float* __restrict__ b_hid,
        const float* __restrict__ alpha,
        unsigned* __restrict__ xbuf,
        unsigned* __restrict__ flags,
        float* __restrict__ out0,
        float* __restrict__ out1) {
    __shared__ uint4 frbuf4[2][64];     // fr as f16 pairs, k-major (2 x 1 KB)
    __shared__ float pbuf[8][256];      // partial dots [w][h_loc]  (8 KB)

    const int t = threadIdx.x;
    const int j = blockIdx.x;
    const int b  = j & 63;
    const int hh = j >> 6;
    const int w = t >> 6, l = t & 63;

    // ---- W into VGPRs: 32 coalesced uint4 loads --------------------------
    uint4 wv[4][8];
    const uint4* wp = Wz4 + ((size_t)(hh * 8 + w) * 4) * 512 + l;
    #pragma unroll
    for (int hi = 0; hi < 4; ++hi)
        #pragma unroll
        for (int g = 0; g < 8; ++g)
            wv[hi][g] = wp[(hi * 8 + g) * 64];
    #pragma unroll
    for (int hi = 0; hi < 4; ++hi)
        #pragma unroll
        for (int g = 0; g < 8; ++g)
            asm volatile("" : "+v"(wv[hi][g].x), "+v"(wv[hi][g].y),
                              "+v"(wv[hi][g].z), "+v"(wv[hi][g].w));

    // ---- init state ------------------------------------------------------
    float v = 0.f, bh = 0.f, al = 0.f, om = 0.f;
    const float* vinp = vin;     // safe defaults, only used when t < 256
    float* o0p = out0;
    float* o1p = out1;
    unsigned short* fr16 = (unsigned short*)frbuf4;   // [2][512]

    if (t < 256) {
        int h = hh * 256 + t;
        v  = init_state[b * H_ + h];
        bh = b_hid[h];
        al = alpha[h];
        om = 1.0f - al;
        fr16[hh * 256 + t] = f32_to_f16b(fmaxf(v, 0.0f));
        vinp = vin  + (size_t)b * T_ * H_ + h;
        o0p  = out0 + (size_t)b * T_ * H_ + h;
        o1p  = out1 + (size_t)b * T_ * H_ + h;
    } else {
        int tp = t - 256;
        float vv = init_state[b * H_ + (hh ^ 1) * 256 + tp];
        fr16[(hh ^ 1) * 256 + tp] = f32_to_f16b(fmaxf(vv, 0.0f));
    }

    unsigned* myxbuf = xbuf + (size_t)(b * 2 + hh) * 512;
    unsigned* paxbuf = xbuf + (size_t)(b * 2 + (hh ^ 1)) * 512;
    unsigned* myflag = flags + j;
    unsigned* paflag = flags + (j ^ 64);

    __syncthreads();

    for (int s = 0; s < T_; ++s) {
        const int par = s & 1;
        float vinv = (t < 256) ? vinp[(size_t)s * H_] : 0.0f;  // early issue

        // ---- phase 1: partial dots over this wave's k-slice --------------
        const uint4* fb = &frbuf4[par][w * 8];    // wave-uniform -> broadcast
        float a0 = 0.f, a1 = 0.f, a2 = 0.f, a3 = 0.f;
        #pragma unroll
        for (int g = 0; g < 8; ++g) {
            uint4 f = fb[g];
            a0 = dot2(f.x, wv[0][g].x, a0);
            a0 = dot2(f.y, wv[0][g].y, a0);
            a0 = dot2(f.z, wv[0][g].z, a0);
            a0 = dot2(f.w, wv[0][g].w, a0);
            a1 = dot2(f.x, wv[1][g].x, a1);
            a1 = dot2(f.y, wv[1][g].y, a1);
            a1 = dot2(f.z, wv[1][g].z, a1);
            a1 = dot2(f.w, wv[1][g].w, a1);
            a2 = dot2(f.x, wv[2][g].x, a2);
            a2 = dot2(f.y, wv[2][g].y, a2);
            a2 = dot2(f.z, wv[2][g].z, a2);
            a2 = dot2(f.w, wv[2][g].w, a2);
            a3 = dot2(f.x, wv[3][g].x, a3);
            a3 = dot2(f.y, wv[3][g].y, a3);
            a3 = dot2(f.z, wv[3][g].z, a3);
            a3 = dot2(f.w, wv[3][g].w, a3);
        }
        pbuf[w][l]       = a0;
        pbuf[w][l + 64]  = a1;
        pbuf[w][l + 128] = a2;
        pbuf[w][l + 192] = a3;

        __syncthreads();   // A: partials visible

        // ---- phase 2 -----------------------------------------------------
        if (t < 256) {
            // finalize h = hh*256 + t
            float sum = pbuf[0][t] + pbuf[1][t] + pbuf[2][t] + pbuf[3][t]
                      + pbuf[4][t] + pbuf[5][t] + pbuf[6][t] + pbuf[7][t];
            float vhid = sum + bh;
            float vnew = om * v + al * (vhid + vinv);
            float vr   = om * vnew + al * vhid;
            v = vnew;
            float frn = fmaxf(vnew, 0.0f);
            float frr = fmaxf(vr, 0.0f);
            o0p[(size_t)s * H_] = frn;
            o1p[(size_t)s * H_] = frr;
            fr16[(par ^ 1) * 512 + hh * 256 + t] = f32_to_f16b(frn);
            if (s < T_ - 1) {
                __hip_atomic_store(&myxbuf[((s + 1) & 1) * 256 + t],
                                   __builtin_bit_cast(unsigned, frn),
                                   __ATOMIC_RELAXED, __HIP_MEMORY_SCOPE_AGENT);
                // per-wave signal: producers never wait on consumers
                if (l == 0)
                    __hip_atomic_fetch_add(myflag, 1u, __ATOMIC_RELEASE,
                                           __HIP_MEMORY_SCOPE_AGENT);
            }
        } else if (s < T_ - 1) {
            // fetch partner's new fr half (produced this step)
            int tp = t - 256;
            unsigned target = 4u * (unsigned)(s + 1);
            while (__hip_atomic_load(paflag, __ATOMIC_ACQUIRE,
                                     __HIP_MEMORY_SCOPE_AGENT) < target)
                __builtin_amdgcn_s_sleep(2);
            unsigned u = __hip_atomic_load(&paxbuf[((s + 1) & 1) * 256 + tp],
                                           __ATOMIC_RELAXED,
                                           __HIP_MEMORY_SCOPE_AGENT);
            float f = __builtin_bit_cast(float, u);
            fr16[(par ^ 1) * 512 + (hh ^ 1) * 256 + tp] = f32_to_f16b(f);
        }

        __syncthreads();   // B: frbuf[par^1] complete; pbuf free for reuse
    }
}

// ---------------------------------------------------------------------------
extern "C" void kernel_launch(void* const* d_in, const int* in_sizes, int n_in,
                              void* d_out, int out_size, void* d_ws, size_t ws_size,
                              hipStream_t stream) {
    const float* x          = (const float*)d_in[0];
    const float* init_state = (const float*)d_in[1];
    const float* W_in       = (const float*)d_in[2];
    const float* b_in       = (const float*)d_in[3];
    const float* W_hid      = (const float*)d_in[4];
    const float* b_hid      = (const float*)d_in[5];
    const float* alpha      = (const float*)d_in[6];

    float* out0 = (float*)d_out;
    float* out1 = out0 + (size_t)B_ * T_ * H_;

    char* ws = (char*)d_ws;
    float*    vin   = (float*)ws;                      // 67,108,864 B
    unsigned* Wz    = (unsigned*)(ws + 67108864);      //    524,288 B
    unsigned* xbuf  = (unsigned*)(ws + 67633152);      //    262,144 B
    unsigned* flags = (unsigned*)(ws + 67895296);      //        512 B

    hipLaunchKernelGGL(wconv, dim3(512), dim3(256), 0, stream,
                       W_hid, Wz, flags);
    hipLaunchKernelGGL(vin_gemm, dim3(512, 8), dim3(256), 0, stream,
                       x, W_in, b_in, vin);
    hipLaunchKernelGGL(recurrent, dim3(128), dim3(512), 0, stream,
                       (const uint4*)Wz, vin, init_state, b_hid, alpha,
                       xbuf, flags, out0, out1);
}

// Round 5
// 967.979 us; speedup vs baseline: 8.5794x; 8.5794x over previous
//
#include <hip/hip_runtime.h>
#include <hip/hip_fp16.h>

#define B_ 64
#define T_ 512
#define I_ 128
#define H_ 512

typedef _Float16 half2v __attribute__((ext_vector_type(2)));

__device__ __forceinline__ float dot2(unsigned a, unsigned b, float c) {
    return __builtin_amdgcn_fdot2(__builtin_bit_cast(half2v, a),
                                  __builtin_bit_cast(half2v, b), c, false);
}

__device__ __forceinline__ unsigned short f32_to_f16b(float f) {
    _Float16 h = (_Float16)f;
    return __builtin_bit_cast(unsigned short, h);
}

// ---------------------------------------------------------------------------
// Kernel 1: W_hid fp32 [H,H] -> packed f16 pairs for `recurrent`.
// Consumer thread (w=t>>6, l=t&63) covers h-slots i in [0,8): h = l + 64*i,
// k-slice of wave w: pairs kp = 32w + 4g + m (g in [0,8), m = dword in uint4).
//  - VGPR part (slots i<6):  uint4 idx ((w*6+i)*8+g)*64 + l   -> dwords [0, 98304)
//  - LDS part  (slots 6,7):  uint4 idx ((w*2+ii)*8+g)*64 + l  -> dwords [98304, 131072)
// ---------------------------------------------------------------------------
__global__ void wconv(const float* __restrict__ Whid,
                      unsigned* __restrict__ Wz) {
    int p = blockIdx.x * 256 + threadIdx.x;   // dword index, 0..131071
    int m  = p & 3;
    int u4 = p >> 2;
    int l, g, w, i;
    if (u4 < 24576) {                 // VGPR part
        l = u4 & 63; g = (u4 >> 6) & 7;
        int r = u4 >> 9;              // 0..47
        w = r / 6; i = r - 6 * w;
    } else {                          // LDS part
        int q = u4 - 24576;           // 0..8191
        l = q & 63; g = (q >> 6) & 7;
        int r = q >> 9;               // 0..15
        w = r >> 1; i = 6 + (r & 1);
    }
    int h  = l + 64 * i;
    int kp = 32 * w + 4 * g + m;
    float w0 = Whid[h * H_ + 2 * kp];
    float w1 = Whid[h * H_ + 2 * kp + 1];
    half2v hw = { (_Float16)w0, (_Float16)w1 };
    Wz[p] = __builtin_bit_cast(unsigned, hw);
}

// ---------------------------------------------------------------------------
// Kernel 2: v_in[b,t,h] = x[b,t,:] @ W_in[h,:] + b_in[h]  (unchanged)
// ---------------------------------------------------------------------------
__global__ __launch_bounds__(256) void vin_gemm(const float* __restrict__ x,
                                                const float* __restrict__ Win,
                                                const float* __restrict__ bin,
                                                float* __restrict__ vin) {
    __shared__ float xs[64][129];
    __shared__ float wsh[64][129];
    const int tid = threadIdx.x;
    const int m0 = blockIdx.x * 64;
    const int n0 = blockIdx.y * 64;

    #pragma unroll
    for (int r = 0; r < 8; ++r) {
        int gi = r * 256 + tid;
        int row = gi >> 5;
        int c4 = (gi & 31) * 4;
        float4 v = ((const float4*)(x + (size_t)(m0 + row) * I_))[gi & 31];
        xs[row][c4] = v.x; xs[row][c4 + 1] = v.y;
        xs[row][c4 + 2] = v.z; xs[row][c4 + 3] = v.w;
        float4 w = ((const float4*)(Win + (size_t)(n0 + row) * I_))[gi & 31];
        wsh[row][c4] = w.x; wsh[row][c4 + 1] = w.y;
        wsh[row][c4 + 2] = w.z; wsh[row][c4 + 3] = w.w;
    }
    __syncthreads();

    const int ty = tid >> 4, tx = tid & 15;
    float acc[4][4] = {};
    #pragma unroll 4
    for (int k = 0; k < 128; ++k) {
        float a[4], bb[4];
        #pragma unroll
        for (int i = 0; i < 4; ++i) a[i] = xs[ty * 4 + i][k];
        #pragma unroll
        for (int j = 0; j < 4; ++j) bb[j] = wsh[tx * 4 + j][k];
        #pragma unroll
        for (int i = 0; i < 4; ++i)
            #pragma unroll
            for (int j = 0; j < 4; ++j)
                acc[i][j] = fmaf(a[i], bb[j], acc[i][j]);
    }

    float4 bv = ((const float4*)(bin + n0))[tx];
    #pragma unroll
    for (int i = 0; i < 4; ++i) {
        int m = m0 + ty * 4 + i;
        float4 o;
        o.x = acc[i][0] + bv.x; o.y = acc[i][1] + bv.y;
        o.z = acc[i][2] + bv.z; o.w = acc[i][3] + bv.w;
        ((float4*)(vin + (size_t)m * H_ + n0))[tx] = o;
    }
}

// ---------------------------------------------------------------------------
// Kernel 3: recurrence, one block per batch, k-split by wave.
// Wave w handles k in [64w, 64w+64); thread (w,l) computes partial dots for
// 8 h-values {l + 64*i}. Per step per wave: only 8 broadcast b128 fr reads
// (vs 64 in R1), 16 lane-distinct ldsW b128, 4 b64 partial writes, 8 b32
// partial reads. All threads produce AND reduce (h = t) -- no divergence,
// no cross-block traffic.
// ---------------------------------------------------------------------------
__global__ __launch_bounds__(512, 2)
__attribute__((amdgpu_waves_per_eu(2, 2)))
void recurrent(
        const uint4* __restrict__ Wz4,
        const float* __restrict__ vin,
        const float* __restrict__ init_state,
        const float* __restrict__ b_hid,
        const float* __restrict__ alpha,
        float* __restrict__ out0,
        float* __restrict__ out1) {
    __shared__ uint4 ldsW[8192];        // 128 KB : W slots 6,7
    __shared__ uint4 frbuf4[2][64];     //   2 KB : fr as f16 pairs, dbuf
    __shared__ float pbuf[8][640];      //  20 KB : partials [w][l*10+i]

    const int t = threadIdx.x;
    const int b = blockIdx.x;
    const int w = t >> 6, l = t & 63;

    // ---- W slots 0..5 into VGPRs: 48 coalesced uint4 loads ---------------
    uint4 wv[6][8];
    const uint4* wp = Wz4 + (size_t)(w * 48) * 64 + l;
    #pragma unroll
    for (int i = 0; i < 6; ++i)
        #pragma unroll
        for (int g = 0; g < 8; ++g)
            wv[i][g] = wp[(i * 8 + g) * 64];
    #pragma unroll
    for (int i = 0; i < 6; ++i)
        #pragma unroll
        for (int g = 0; g < 8; ++g)
            asm volatile("" : "+v"(wv[i][g].x), "+v"(wv[i][g].y),
                              "+v"(wv[i][g].z), "+v"(wv[i][g].w));

    // ---- W slots 6,7 into LDS: 16 b128 per thread, linear ----------------
    const uint4* lsrc = Wz4 + 24576;
    #pragma unroll
    for (int kk = 0; kk < 16; ++kk) ldsW[kk * 512 + t] = lsrc[kk * 512 + t];

    // ---- init ------------------------------------------------------------
    unsigned short* fr16 = (unsigned short*)frbuf4;   // [2][512]
    float v = init_state[b * H_ + t];
    fr16[t] = f32_to_f16b(fmaxf(v, 0.0f));
    const float bh = b_hid[t];
    const float al = alpha[t];
    const float om = 1.0f - al;

    const float* vinp = vin + (size_t)b * T_ * H_ + t;
    float* o0 = out0 + (size_t)b * T_ * H_ + t;
    float* o1 = out1 + (size_t)b * T_ * H_ + t;

    const int lw0 = (w * 2) * 8 * 64 + l;     // uint4 base, slot 6
    float* prow = &pbuf[w][l * 10];           // this thread's 8 partials

    __syncthreads();

    for (int s = 0; s < T_; ++s) {
        const int par = s & 1;
        float vinv = vinp[(size_t)s * H_];        // early issue, used late

        const uint4* fb = &frbuf4[par][w * 8];    // wave-uniform -> broadcast
        float a0 = 0.f, a1 = 0.f, a2 = 0.f, a3 = 0.f;
        float a4 = 0.f, a5 = 0.f, a6 = 0.f, a7 = 0.f;

        #pragma unroll
        for (int g = 0; g < 8; ++g) {
            uint4 wl0 = ldsW[lw0 + g * 64];       // lane-consecutive b128
            uint4 wl1 = ldsW[lw0 + 512 + g * 64];
            uint4 f = fb[g];                      // broadcast b128
            a0 = dot2(f.x, wv[0][g].x, a0); a0 = dot2(f.y, wv[0][g].y, a0);
            a0 = dot2(f.z, wv[0][g].z, a0); a0 = dot2(f.w, wv[0][g].w, a0);
            a1 = dot2(f.x, wv[1][g].x, a1); a1 = dot2(f.y, wv[1][g].y, a1);
            a1 = dot2(f.z, wv[1][g].z, a1); a1 = dot2(f.w, wv[1][g].w, a1);
            a2 = dot2(f.x, wv[2][g].x, a2); a2 = dot2(f.y, wv[2][g].y, a2);
            a2 = dot2(f.z, wv[2][g].z, a2); a2 = dot2(f.w, wv[2][g].w, a2);
            a3 = dot2(f.x, wv[3][g].x, a3); a3 = dot2(f.y, wv[3][g].y, a3);
            a3 = dot2(f.z, wv[3][g].z, a3); a3 = dot2(f.w, wv[3][g].w, a3);
            a4 = dot2(f.x, wv[4][g].x, a4); a4 = dot2(f.y, wv[4][g].y, a4);
            a4 = dot2(f.z, wv[4][g].z, a4); a4 = dot2(f.w, wv[4][g].w, a4);
            a5 = dot2(f.x, wv[5][g].x, a5); a5 = dot2(f.y, wv[5][g].y, a5);
            a5 = dot2(f.z, wv[5][g].z, a5); a5 = dot2(f.w, wv[5][g].w, a5);
            a6 = dot2(f.x, wl0.x, a6); a6 = dot2(f.y, wl0.y, a6);
            a6 = dot2(f.z, wl0.z, a6); a6 = dot2(f.w, wl0.w, a6);
            a7 = dot2(f.x, wl1.x, a7); a7 = dot2(f.y, wl1.y, a7);
            a7 = dot2(f.z, wl1.z, a7); a7 = dot2(f.w, wl1.w, a7);
        }

        // partial writes: 4 x b64, stride-10 rows -> 2 lanes/bank (free)
        float2* pr = (float2*)prow;
        pr[0] = make_float2(a0, a1);
        pr[1] = make_float2(a2, a3);
        pr[2] = make_float2(a4, a5);
        pr[3] = make_float2(a6, a7);

        __syncthreads();   // A: partials visible

        // reduction: thread t reduces h = t (hl = l, hi = w)
        float sum = pbuf[0][l * 10 + w] + pbuf[1][l * 10 + w]
                  + pbuf[2][l * 10 + w] + pbuf[3][l * 10 + w]
                  + pbuf[4][l * 10 + w] + pbuf[5][l * 10 + w]
                  + pbuf[6][l * 10 + w] + pbuf[7][l * 10 + w];

        float vhid = sum + bh;
        float vnew = om * v + al * (vhid + vinv);
        float vr   = om * vnew + al * vhid;
        v = vnew;
        float frn = fmaxf(vnew, 0.0f);
        float frr = fmaxf(vr, 0.0f);

        o0[(size_t)s * H_] = frn;
        o1[(size_t)s * H_] = frr;
        fr16[(par ^ 1) * 512 + t] = f32_to_f16b(frn);

        __syncthreads();   // B: new fr complete; pbuf free for next step
    }
}

// ---------------------------------------------------------------------------
extern "C" void kernel_launch(void* const* d_in, const int* in_sizes, int n_in,
                              void* d_out, int out_size, void* d_ws, size_t ws_size,
                              hipStream_t stream) {
    const float* x          = (const float*)d_in[0];
    const float* init_state = (const float*)d_in[1];
    const float* W_in       = (const float*)d_in[2];
    const float* b_in       = (const float*)d_in[3];
    const float* W_hid      = (const float*)d_in[4];
    const float* b_hid      = (const float*)d_in[5];
    const float* alpha      = (const float*)d_in[6];

    float* out0 = (float*)d_out;
    float* out1 = out0 + (size_t)B_ * T_ * H_;

    char* ws = (char*)d_ws;
    float*    vin = (float*)ws;                    // 67,108,864 B
    unsigned* Wz  = (unsigned*)(ws + 67108864);    //    524,288 B

    hipLaunchKernelGGL(wconv, dim3(512), dim3(256), 0, stream,
                       W_hid, Wz);
    hipLaunchKernelGGL(vin_gemm, dim3(512, 8), dim3(256), 0, stream,
                       x, W_in, b_in, vin);
    hipLaunchKernelGGL(recurrent, dim3(64), dim3(512), 0, stream,
                       (const uint4*)Wz, vin, init_state, b_hid, alpha,
                       out0, out1);
}